// Round 11
// baseline (66.440 us; speedup 1.0000x reference)
//
#include <hip/hip_runtime.h>
#include <hip/hip_bf16.h>

// loss = mean((output-target)^2) + ALPHA * sum(masked cosine Gram of
// V[128][196608]), V[f][d] = conv_w[o][i][f][k], d=(site,k), site=(o,i).
//
// Round 11: 24-wave gram. 512 blocks x 512 threads (8 waves x 16 rows,
// acc0[8]=32 regs); single 26.6KB bf16 tile; launch_bounds(512,6) -> <=85
// VGPR -> 3 blocks/CU = 24 waves/CU (r10 had 16). Zero read redundancy.
// MSE standalone at its proven 32-wave config. Partials pack column pairs
// (c, c+64) -- same wave owns both halves. reduce unchanged; finalize
// remapped.

typedef __attribute__((ext_vector_type(8))) short bf16x8;   // 8 bf16 = 4 VGPR
typedef __attribute__((ext_vector_type(4))) float f32x4;

#define ALPHA 0.0005f
#define TAU 0.2f

#define FDIM 128
#define TSTRIDE 52          // tile row stride in dwords (48 data + 4 pad)
#define GRAM_NBLK 512
#define CHUNK_F4 3072       // 32 sites * 96 float4
#define GRAM_ELEMS 16384
#define NPAIRQ 8192         // packed u32 per partial tile
#define MSE_N4 2048000      // 8192*1000/4
#define MSE_NBLK 2048

// branchless RNE f32->bf16 pair pack
__device__ __forceinline__ unsigned int pack_bf2(float lo, float hi) {
    union { float f; unsigned int u; } a, b;
    a.f = lo; b.f = hi;
    unsigned int al = (a.u + 0x7fffu + ((a.u >> 16) & 1u)) >> 16;
    unsigned int bh = (b.u + 0x7fffu + ((b.u >> 16) & 1u)) & 0xffff0000u;
    return (al & 0xffffu) | bh;
}

// ---------------------------------------------------------------- MSE kernel
// 2048 blocks x 256 thr, 0 LDS -> 8 blocks/CU = 32 waves/CU (proven regime).
__global__ void __launch_bounds__(256) mse_kernel(
        const float* __restrict__ o, const float* __restrict__ t,
        float* __restrict__ mse_part) {
    __shared__ float red[4];
    const int tid = threadIdx.x;
    const float4* o4 = reinterpret_cast<const float4*>(o);
    const float4* t4 = reinterpret_cast<const float4*>(t);
    float s = 0.f;
    for (int i = blockIdx.x * 256 + tid; i < MSE_N4; i += MSE_NBLK * 256) {
        float4 a = o4[i], b = t4[i];
        float dx = a.x - b.x, dy = a.y - b.y, dz = a.z - b.z, dw = a.w - b.w;
        s += dx * dx + dy * dy + dz * dz + dw * dw;
    }
    for (int off = 32; off; off >>= 1) s += __shfl_down(s, off);
    if ((tid & 63) == 0) red[tid >> 6] = s;
    __syncthreads();
    if (tid == 0) mse_part[blockIdx.x] = red[0] + red[1] + red[2] + red[3];
}

// --------------------------------------------------------------- Gram kernel
// 512 blocks x 512 thr (8 waves), 3 blocks/CU. Per chunk (32 sites):
// stage+convert fp32->bf16 tile (6 loads + 12 packed b32 writes per thread),
// 2 barriers, 3 K-steps x (1 A-frag + 8 B-frags + 8 MFMA) per wave.
// Wave w owns rows [16w, 16w+16).
__global__ void __launch_bounds__(512, 6) gram_kernel(
        const float* __restrict__ conv, unsigned int* __restrict__ pp) {
    __shared__ unsigned int tile[FDIM * TSTRIDE];   // 26624 B
    const int tid = threadIdx.x;
    const int lane = tid & 63;
    const int wave = tid >> 6;                  // 0..7
    const int sp = tid >> 5;                    // site pair 0..15
    const int q = tid & 31;                     // f32x4 sub-offset 0..31
    const int colr = lane & 15;
    const int hi8 = (lane >> 4) * 8;
    const unsigned short* tileu = reinterpret_cast<const unsigned short*>(tile);

    f32x4 acc0[8];
#pragma unroll
    for (int cc = 0; cc < 8; ++cc) acc0[cc] = (f32x4)0.f;

    const f32x4* src4 = reinterpret_cast<const f32x4*>(conv);
    const size_t cb = (size_t)blockIdx.x * (4 * CHUNK_F4) + sp * 192 + q;

    for (int c = 0; c < 4; ++c) {
        __syncthreads();                        // tile free (prev mfma done)
        // 6 independent loads (2 sites x 3), then convert+write
        f32x4 V0[3], V1[3];
#pragma unroll
        for (int it = 0; it < 3; ++it) {
            V0[it] = src4[cb + c * CHUNK_F4 + 32 * it];
            V1[it] = src4[cb + c * CHUNK_F4 + 96 + 32 * it];
        }
#pragma unroll
        for (int it = 0; it < 3; ++it)
#pragma unroll
            for (int u = 0; u < 4; ++u) {
                const int idx = (q + 32 * it) * 4 + u;  // [0,384): f*3 + k
                const int f = idx / 3;                  // magic-mul
                const int k = idx - 3 * f;
                tile[f * TSTRIDE + k * 16 + sp] = pack_bf2(V0[it][u], V1[it][u]);
            }
        __syncthreads();                        // tile ready
#pragma unroll
        for (int ks = 0; ks < 3; ++ks) {
            const int koff = ks * 32 + hi8;
            bf16x8 a0 = *reinterpret_cast<const bf16x8*>(
                &tileu[(wave * 16 + colr) * (TSTRIDE * 2) + koff]);
#pragma unroll
            for (int cc = 0; cc < 8; ++cc) {
                bf16x8 b = *reinterpret_cast<const bf16x8*>(
                    &tileu[(cc * 16 + colr) * (TSTRIDE * 2) + koff]);
                acc0[cc] = __builtin_amdgcn_mfma_f32_16x16x32_bf16(a0, b, acc0[cc], 0, 0, 0);
            }
        }
    }

    // epilogue: bf16 COLUMN-pair pack: u32[row*64 + c] = pack(G[row][c],
    // G[row][c+64]), c<64; row = 16*wave + rsub + j (C/D layout: col=lane&15,
    // row=(lane>>4)*4+j -- validated).
    unsigned int* myp = pp + (size_t)blockIdx.x * NPAIRQ;
    const int rsub = (lane >> 4) << 2;
#pragma unroll
    for (int cc = 0; cc < 4; ++cc) {
        const int clo = cc * 16 + colr;
#pragma unroll
        for (int j = 0; j < 4; ++j) {
            const int row = wave * 16 + rsub + j;
            myp[row * 64 + clo] = pack_bf2(acc0[cc][j], acc0[cc + 4][j]);
        }
    }
}

// ------------------------------------------------- partial reduce (bf16 pairs)
// 512 blocks x 256 thr: block owns 16 packed entries; 16 slices of 32 tiles.
__global__ void __launch_bounds__(256) reduce_kernel(
        const unsigned int* __restrict__ pp, float* __restrict__ gram) {
    __shared__ float red[16][16][2];
    const int tid = threadIdx.x;
    const int u = tid & 15;
    const int s = tid >> 4;                 // 0..15
    const int qq = blockIdx.x * 16 + u;
    float lo = 0.f, hi = 0.f;
#pragma unroll 8
    for (int b = s * 32; b < s * 32 + 32; ++b) {
        const unsigned int v = pp[(size_t)b * NPAIRQ + qq];
        lo += __uint_as_float(v << 16);
        hi += __uint_as_float(v & 0xffff0000u);
    }
    red[s][u][0] = lo; red[s][u][1] = hi;
    __syncthreads();
    if (tid < 32) {
        const int u2 = tid >> 1, h = tid & 1;
        float x = 0.f;
#pragma unroll
        for (int s2 = 0; s2 < 16; ++s2) x += red[s2][u2][h];
        gram[(blockIdx.x * 16 + u2) * 2 + h] = x;
    }
}

// ------------------------------------------------------------ finalize
// gram layout: g = (row*64 + c)*2 + h, col = c + 64h (c<64).
__global__ void __launch_bounds__(256) finalize_kernel(
        const float* __restrict__ gram, const float* __restrict__ mse_part,
        float* __restrict__ out) {
    __shared__ float rn[FDIM];
    __shared__ float redS[4], redM[4];
    const int tid = threadIdx.x;
    if (tid < FDIM) {
        const int r = tid;
        rn[r] = rsqrtf(gram[(r * 64 + (r & 63)) * 2 + (r >> 6)]);
    }
    __syncthreads();
    float s = 0.f;
    for (int i = tid; i < GRAM_ELEMS; i += 256) {
        const int h = i & 1;
        const int qq = i >> 1;
        const int row = qq >> 6;
        const int col = (qq & 63) | (h << 6);
        const float gv = gram[i] * rn[row] * rn[col];
        if (row != col && gv > TAU && gv <= 1.0f) s += gv;
    }
    float m = 0.f;
#pragma unroll 8
    for (int j = 0; j < 8; ++j) m += mse_part[tid * 8 + j];   // 2048 entries
    for (int off = 32; off; off >>= 1) {
        s += __shfl_down(s, off);
        m += __shfl_down(m, off);
    }
    if ((tid & 63) == 0) { redS[tid >> 6] = s; redM[tid >> 6] = m; }
    __syncthreads();
    if (tid == 0)
        out[0] = (redM[0] + redM[1] + redM[2] + redM[3]) * (1.0f / 8192000.0f) +
                 ALPHA * (redS[0] + redS[1] + redS[2] + redS[3]);
}

extern "C" void kernel_launch(void* const* d_in, const int* in_sizes, int n_in,
                              void* d_out, int out_size, void* d_ws, size_t ws_size,
                              hipStream_t stream) {
    const float* output = (const float*)d_in[0];
    const float* target = (const float*)d_in[1];
    const float* conv   = (const float*)d_in[2];
    float* out = (float*)d_out;

    float* wsf       = (float*)d_ws;
    float* mse_part  = wsf;                              // 2048 floats
    float* gram      = wsf + MSE_NBLK;                   // 16384 floats
    unsigned int* pp = (unsigned int*)(wsf + MSE_NBLK + GRAM_ELEMS); // 16.8 MB
    (void)ws_size;   // need ~16.9 MB; harness provides ~402 MB (r5 profile)

    // all buffers fully written before read -> no memsets
    gram_kernel<<<GRAM_NBLK, 512, 0, stream>>>(conv, pp);
    mse_kernel<<<MSE_NBLK, 256, 0, stream>>>(output, target, mse_part);
    reduce_kernel<<<NPAIRQ / 16, 256, 0, stream>>>(pp, gram);
    finalize_kernel<<<1, 256, 0, stream>>>(gram, mse_part, out);
}